// Round 8
// baseline (174.615 us; speedup 1.0000x reference)
//
#include <hip/hip_runtime.h>
#include <hip/hip_bf16.h>
#include <math.h>

#define N_TRACK 50000
#define N_LANE  50000
#define N_ATT   (N_TRACK + N_LANE)
#define NP_T    1000000
#define NP_L    500000
#define E_ATT   1600000
#define HEADS   30
#define EPS     1e-5f
#define NEG_SLOPE 0.2f

// native vector types for nontemporal builtins (HIP_vector_type is rejected)
typedef __attribute__((ext_vector_type(4))) float nfloat4;
typedef __attribute__((ext_vector_type(2))) float nfloat2;

// Packed per-node record: 30 heads x (h0,h1) as bf16 pair in one dword,
// padded to 32 dwords = 128 B = exactly ONE cache line per node.
#define REC_DW 32

// point kernel thread count: 500K track-pairs + 250K lane-pairs, padded to
// 800K so the fused edge-boundary scan covers E_ATT = 2 x 800K exactly.
#define PT_THREADS 800000

// ---------------- Merged point MLP (2 pts/thread) + segment max + fused off[] scan ----------------
__global__ void point_kernel(const nfloat4* __restrict__ xt, const nfloat2* __restrict__ xl,
                             const int* __restrict__ idt, const int* __restrict__ idl,
                             const float* __restrict__ tW, const float* __restrict__ tb,
                             const float* __restrict__ tg, const float* __restrict__ tbeta,
                             const float* __restrict__ lW, const float* __restrict__ lb,
                             const float* __restrict__ lg, const float* __restrict__ lbeta,
                             const int* __restrict__ att_dst,
                             float* __restrict__ pool_t, float* __restrict__ pool_l,
                             int* __restrict__ off) {
    int t = blockIdx.x * blockDim.x + threadIdx.x;
    if (t >= PT_THREADS) return;
    int lane = threadIdx.x & 63;

    // ---- fused per-dst edge offsets: boundary scan over sorted att_dst ----
    #pragma unroll
    for (int r = 0; r < 2; r++) {
        int eix = t + r * PT_THREADS;
        int d1 = att_dst[eix];
        int d0 = (eix == 0) ? -1 : att_dst[eix - 1];
        int jmax = (d1 < N_TRACK) ? d1 : N_TRACK;
        for (int j = d0 + 1; j <= jmax; j++) off[j] = eix;
        if (eix == E_ATT - 1)
            for (int j = d1 + 1; j <= N_TRACK; j++) off[j] = E_ATT;
    }

    // ---- per-point MLP, two points per thread ----
    int id = -1;
    float y0 = 0.f, y1 = 0.f, y2 = 0.f, y3 = 0.f;

    if (t < NP_T / 2) {
        nfloat4 xv0 = __builtin_nontemporal_load(&xt[2 * t]);
        nfloat4 xv1 = __builtin_nontemporal_load(&xt[2 * t + 1]);
        float ya[4], yb[4];
        {
            float h[4];
            #pragma unroll
            for (int j = 0; j < 4; j++)
                h[j] = xv0.x * tW[0*4+j] + xv0.y * tW[1*4+j] + xv0.z * tW[2*4+j] + xv0.w * tW[3*4+j] + tb[j];
            float mu = 0.25f * (h[0] + h[1] + h[2] + h[3]);
            float var = 0.f;
            #pragma unroll
            for (int j = 0; j < 4; j++) { float d = h[j] - mu; var += d * d; }
            float rr = rsqrtf(var * 0.25f + EPS);
            #pragma unroll
            for (int j = 0; j < 4; j++) ya[j] = fmaxf((h[j] - mu) * rr * tg[j] + tbeta[j], 0.f);
        }
        {
            float h[4];
            #pragma unroll
            for (int j = 0; j < 4; j++)
                h[j] = xv1.x * tW[0*4+j] + xv1.y * tW[1*4+j] + xv1.z * tW[2*4+j] + xv1.w * tW[3*4+j] + tb[j];
            float mu = 0.25f * (h[0] + h[1] + h[2] + h[3]);
            float var = 0.f;
            #pragma unroll
            for (int j = 0; j < 4; j++) { float d = h[j] - mu; var += d * d; }
            float rr = rsqrtf(var * 0.25f + EPS);
            #pragma unroll
            for (int j = 0; j < 4; j++) yb[j] = fmaxf((h[j] - mu) * rr * tg[j] + tbeta[j], 0.f);
        }
        int2 ids = *(const int2*)&idt[2 * t];
        if (ids.x == ids.y) {
            yb[0] = fmaxf(yb[0], ya[0]); yb[1] = fmaxf(yb[1], ya[1]);
            yb[2] = fmaxf(yb[2], ya[2]); yb[3] = fmaxf(yb[3], ya[3]);
        } else {
            unsigned int* p = (unsigned int*)&pool_t[(size_t)ids.x * 4];
            atomicMax(p + 0, __float_as_uint(ya[0]));
            atomicMax(p + 1, __float_as_uint(ya[1]));
            atomicMax(p + 2, __float_as_uint(ya[2]));
            atomicMax(p + 3, __float_as_uint(ya[3]));
        }
        id = ids.y;
        y0 = yb[0]; y1 = yb[1]; y2 = yb[2]; y3 = yb[3];
    } else if (t < NP_T / 2 + NP_L / 2) {
        int u = t - NP_T / 2;
        nfloat2 xv0 = __builtin_nontemporal_load(&xl[2 * u]);
        nfloat2 xv1 = __builtin_nontemporal_load(&xl[2 * u + 1]);
        float ya[2], yb[2];
        {
            float h0 = xv0.x * lW[0] + xv0.y * lW[2] + lb[0];
            float h1 = xv0.x * lW[1] + xv0.y * lW[3] + lb[1];
            float mu = 0.5f * (h0 + h1);
            float var = 0.5f * ((h0 - mu) * (h0 - mu) + (h1 - mu) * (h1 - mu));
            float rr = rsqrtf(var + EPS);
            ya[0] = fmaxf((h0 - mu) * rr * lg[0] + lbeta[0], 0.f);
            ya[1] = fmaxf((h1 - mu) * rr * lg[1] + lbeta[1], 0.f);
        }
        {
            float h0 = xv1.x * lW[0] + xv1.y * lW[2] + lb[0];
            float h1 = xv1.x * lW[1] + xv1.y * lW[3] + lb[1];
            float mu = 0.5f * (h0 + h1);
            float var = 0.5f * ((h0 - mu) * (h0 - mu) + (h1 - mu) * (h1 - mu));
            float rr = rsqrtf(var + EPS);
            yb[0] = fmaxf((h0 - mu) * rr * lg[0] + lbeta[0], 0.f);
            yb[1] = fmaxf((h1 - mu) * rr * lg[1] + lbeta[1], 0.f);
        }
        int2 ids = *(const int2*)&idl[2 * u];
        if (ids.x == ids.y) {
            yb[0] = fmaxf(yb[0], ya[0]); yb[1] = fmaxf(yb[1], ya[1]);
        } else {
            unsigned int* p = (unsigned int*)&pool_l[(size_t)ids.x * 2];
            atomicMax(p + 0, __float_as_uint(ya[0]));
            atomicMax(p + 1, __float_as_uint(ya[1]));
        }
        id = N_TRACK + ids.y;
        y0 = yb[0]; y1 = yb[1];
    }

    // wave-level segmented max scan over each thread's LAST point
    #pragma unroll
    for (int d = 1; d < 64; d <<= 1) {
        int oid = __shfl_down(id, d, 64);
        float o0 = __shfl_down(y0, d, 64);
        float o1 = __shfl_down(y1, d, 64);
        float o2 = __shfl_down(y2, d, 64);
        float o3 = __shfl_down(y3, d, 64);
        if (oid == id) {
            y0 = fmaxf(y0, o0); y1 = fmaxf(y1, o1);
            y2 = fmaxf(y2, o2); y3 = fmaxf(y3, o3);
        }
    }
    int pid = __shfl_up(id, 1, 64);
    bool head = (lane == 0) || (pid != id);
    if (id >= 0 && head) {
        if (id < N_TRACK) {
            unsigned int* p = (unsigned int*)&pool_t[(size_t)id * 4];
            atomicMax(p + 0, __float_as_uint(y0));
            atomicMax(p + 1, __float_as_uint(y1));
            atomicMax(p + 2, __float_as_uint(y2));
            atomicMax(p + 3, __float_as_uint(y3));
        } else {
            unsigned int* p = (unsigned int*)&pool_l[(size_t)(id - N_TRACK) * 2];
            atomicMax(p + 0, __float_as_uint(y0));
            atomicMax(p + 1, __float_as_uint(y1));
        }
    }
}

// ---------------- Node stage: pool -> feats(10) -> h(60) -> bf16-packed line ----------------
__global__ void node_kernel(const float* __restrict__ pool_t, const float* __restrict__ pool_l,
                            const float* __restrict__ tW, const float* __restrict__ tb,
                            const float* __restrict__ lW, const float* __restrict__ lb,
                            const float* __restrict__ fcW,
                            unsigned int* __restrict__ hpack) {
    int i = blockIdx.x * blockDim.x + threadIdx.x;
    if (i >= N_ATT) return;

    float f[10];
    if (i < N_TRACK) {
        const float4 p = *(const float4*)(pool_t + (size_t)i * 4);
        #pragma unroll
        for (int j = 0; j < 10; j++)
            f[j] = p.x * tW[0*10+j] + p.y * tW[1*10+j] + p.z * tW[2*10+j] + p.w * tW[3*10+j] + tb[j];
    } else {
        const float2 p = *(const float2*)(pool_l + (size_t)(i - N_TRACK) * 2);
        #pragma unroll
        for (int j = 0; j < 10; j++)
            f[j] = p.x * lW[0*10+j] + p.y * lW[1*10+j] + lb[j];
    }

    unsigned int rec[REC_DW];
    #pragma unroll
    for (int hh = 0; hh < HEADS; hh++) {
        float a0 = 0.f, a1 = 0.f;
        #pragma unroll
        for (int k = 0; k < 10; k++) {
            a0 += f[k] * fcW[k * 60 + 2 * hh];
            a1 += f[k] * fcW[k * 60 + 2 * hh + 1];
        }
        unsigned int b0 = (unsigned int)__hip_bfloat16_raw(__float2bfloat16(a0)).x;
        unsigned int b1 = (unsigned int)__hip_bfloat16_raw(__float2bfloat16(a1)).x;
        rec[hh] = b0 | (b1 << 16);
    }
    rec[30] = 0u; rec[31] = 0u;

    uint4* rp = (uint4*)(hpack + (size_t)i * REC_DW);
    #pragma unroll
    for (int q = 0; q < 8; q++)
        rp[q] = make_uint4(rec[4*q], rec[4*q+1], rec[4*q+2], rec[4*q+3]);
}

// ---------------- Edge softmax + aggregate: 32-lane group per dst, lane = head ----------------
// Batch-16 gathers into registers; batch softmax: tree-max (no serial per-edge
// chain), ONE accumulator rescale per batch, exp(-inf)=0 makes padding free.
__global__ void edge_kernel(const int* __restrict__ src, const int* __restrict__ off,
                            const unsigned int* __restrict__ hpack,
                            const float* __restrict__ attn_l, const float* __restrict__ attn_r,
                            const float* __restrict__ bias, float* __restrict__ out) {
    int grp = blockIdx.x * 8 + (threadIdx.x >> 5);
    int hh = threadIdx.x & 31;
    if (grp >= N_TRACK || hh >= HEADS) return;

    float al0 = attn_l[2 * hh], al1 = attn_l[2 * hh + 1];
    float ar0 = attn_r[2 * hh], ar1 = attn_r[2 * hh + 1];

    unsigned int dd = hpack[(size_t)grp * REC_DW + hh];
    float er = __uint_as_float(dd << 16) * ar0 + __uint_as_float(dd & 0xffff0000u) * ar1;

    int s = off[grp], e = off[grp + 1];
    float m = -INFINITY;
    float den_a = 0.f, n0_a = 0.f, n1_a = 0.f;
    float den_b = 0.f, n0_b = 0.f, n1_b = 0.f;

    for (int kk = s; kk < e; kk += 16) {
        int sv[16];
        #pragma unroll
        for (int j = 0; j < 16; j++) sv[j] = src[kk + j < e ? kk + j : kk];
        unsigned int d[16];
        #pragma unroll
        for (int j = 0; j < 16; j++) d[j] = hpack[(size_t)sv[j] * REC_DW + hh];

        float h0[16], h1[16], ev[16];
        #pragma unroll
        for (int j = 0; j < 16; j++) {
            h0[j] = __uint_as_float(d[j] << 16);
            h1[j] = __uint_as_float(d[j] & 0xffff0000u);
            float x = h0[j] * al0 + h1[j] * al1 + er;
            x = (x > 0.f) ? x : NEG_SLOPE * x;
            ev[j] = (kk + j < e) ? x : -INFINITY;
        }
        float mx[8];
        #pragma unroll
        for (int j = 0; j < 8; j++) mx[j] = fmaxf(ev[j], ev[j + 8]);
        #pragma unroll
        for (int j = 0; j < 4; j++) mx[j] = fmaxf(mx[j], mx[j + 4]);
        float bm = fmaxf(fmaxf(mx[0], mx[1]), fmaxf(mx[2], mx[3]));

        float nm = fmaxf(m, bm);
        float sc = (m > -INFINITY) ? __expf(m - nm) : 0.f;
        den_a *= sc; n0_a *= sc; n1_a *= sc;
        den_b *= sc; n0_b *= sc; n1_b *= sc;
        m = nm;
        #pragma unroll
        for (int j = 0; j < 16; j += 2) {
            float wa = __expf(ev[j] - nm);
            float wb = __expf(ev[j + 1] - nm);
            den_a += wa;            den_b += wb;
            n0_a += wa * h0[j];     n0_b += wb * h0[j + 1];
            n1_a += wa * h1[j];     n1_b += wb * h1[j + 1];
        }
    }

    float den = den_a + den_b, n0 = n0_a + n0_b, n1 = n1_a + n1_b;
    float o0 = 0.f, o1 = 0.f;
    if (den > 0.f) {
        float inv = 1.f / den;
        o0 = n0 * inv; o1 = n1 * inv;
    }
    nfloat2 v = { o0 + bias[2 * hh], o1 + bias[2 * hh + 1] };
    __builtin_nontemporal_store(v, (nfloat2*)out + (size_t)grp * HEADS + hh);
}

extern "C" void kernel_launch(void* const* d_in, const int* in_sizes, int n_in,
                              void* d_out, int out_size, void* d_ws, size_t ws_size,
                              hipStream_t stream) {
    const nfloat4* track_pts = (const nfloat4*)d_in[0];
    const nfloat2* lane_pts  = (const nfloat2*)d_in[1];
    const int* pt_track_id  = (const int*)d_in[2];
    const int* pt_lane_id   = (const int*)d_in[3];
    const int* att_src      = (const int*)d_in[4];
    const int* att_dst      = (const int*)d_in[5];
    const float* track_mlp_W = (const float*)d_in[6];
    const float* track_mlp_b = (const float*)d_in[7];
    const float* track_ln_g  = (const float*)d_in[8];
    const float* track_ln_b  = (const float*)d_in[9];
    const float* track_out_W = (const float*)d_in[10];
    const float* track_out_b = (const float*)d_in[11];
    const float* lane_mlp_W  = (const float*)d_in[12];
    const float* lane_mlp_b  = (const float*)d_in[13];
    const float* lane_ln_g   = (const float*)d_in[14];
    const float* lane_ln_b   = (const float*)d_in[15];
    const float* lane_out_W  = (const float*)d_in[16];
    const float* lane_out_b  = (const float*)d_in[17];
    const float* gat_fc_W    = (const float*)d_in[18];
    const float* gat_attn_l  = (const float*)d_in[19];
    const float* gat_attn_r  = (const float*)d_in[20];
    const float* gat_bias    = (const float*)d_in[21];
    float* out = (float*)d_out;

    // workspace layout (hpack 128B-aligned: offsets are multiples of 128 B from d_ws)
    float* pool_t = (float*)d_ws;                        // 200000 floats
    float* pool_l = pool_t + 200000;                     // 100000 floats
    int*   off    = (int*)(pool_l + 100000);             // 50001 ints (pad to 50016)
    unsigned int* hpack = (unsigned int*)(off + 50016);  // 100000 * 32 dwords (12.8 MB)

    // zero the pools (ReLU outputs >= 0, empty segments -> 0)
    (void)hipMemsetAsync(d_ws, 0, 300000 * sizeof(float), stream);

    point_kernel<<<(PT_THREADS + 255) / 256, 256, 0, stream>>>(
        track_pts, lane_pts, pt_track_id, pt_lane_id,
        track_mlp_W, track_mlp_b, track_ln_g, track_ln_b,
        lane_mlp_W, lane_mlp_b, lane_ln_g, lane_ln_b,
        att_dst, pool_t, pool_l, off);
    node_kernel<<<(N_ATT + 255) / 256, 256, 0, stream>>>(
        pool_t, pool_l, track_out_W, track_out_b, lane_out_W, lane_out_b,
        gat_fc_W, hpack);
    edge_kernel<<<(N_TRACK + 7) / 8, 256, 0, stream>>>(
        att_src, off, hpack, gat_attn_l, gat_attn_r, gat_bias, out);
}

// Round 9
// 168.757 us; speedup vs baseline: 1.0347x; 1.0347x over previous
//
#include <hip/hip_runtime.h>
#include <hip/hip_bf16.h>
#include <math.h>

#define N_TRACK 50000
#define N_LANE  50000
#define N_ATT   (N_TRACK + N_LANE)
#define NP_T    1000000
#define NP_L    500000
#define E_ATT   1600000
#define HEADS   30
#define EPS     1e-5f
#define NEG_SLOPE 0.2f

// native vector types for nontemporal builtins (HIP_vector_type is rejected)
typedef __attribute__((ext_vector_type(4))) float nfloat4;
typedef __attribute__((ext_vector_type(2))) float nfloat2;

// Packed per-node record: 30 heads x (h0,h1) as bf16 pair in one dword,
// padded to 32 dwords = 128 B = exactly ONE cache line per node.
#define REC_DW 32

// point kernel thread count: 500K track-pairs + 250K lane-pairs, padded to
// 800K so the fused edge-boundary scan covers E_ATT = 2 x 800K exactly.
#define PT_THREADS 800000

// ---------------- Merged point MLP (2 pts/thread) + segment max + fused off[] scan ----------------
__global__ void point_kernel(const nfloat4* __restrict__ xt, const nfloat2* __restrict__ xl,
                             const int* __restrict__ idt, const int* __restrict__ idl,
                             const float* __restrict__ tW, const float* __restrict__ tb,
                             const float* __restrict__ tg, const float* __restrict__ tbeta,
                             const float* __restrict__ lW, const float* __restrict__ lb,
                             const float* __restrict__ lg, const float* __restrict__ lbeta,
                             const int* __restrict__ att_dst,
                             float* __restrict__ pool_t, float* __restrict__ pool_l,
                             int* __restrict__ off) {
    int t = blockIdx.x * blockDim.x + threadIdx.x;
    if (t >= PT_THREADS) return;
    int lane = threadIdx.x & 63;

    // ---- fused per-dst edge offsets: boundary scan over sorted att_dst ----
    #pragma unroll
    for (int r = 0; r < 2; r++) {
        int eix = t + r * PT_THREADS;
        int d1 = att_dst[eix];
        int d0 = (eix == 0) ? -1 : att_dst[eix - 1];
        int jmax = (d1 < N_TRACK) ? d1 : N_TRACK;
        for (int j = d0 + 1; j <= jmax; j++) off[j] = eix;
        if (eix == E_ATT - 1)
            for (int j = d1 + 1; j <= N_TRACK; j++) off[j] = E_ATT;
    }

    // ---- per-point MLP, two points per thread ----
    int id = -1;
    float y0 = 0.f, y1 = 0.f, y2 = 0.f, y3 = 0.f;

    if (t < NP_T / 2) {
        nfloat4 xv0 = __builtin_nontemporal_load(&xt[2 * t]);
        nfloat4 xv1 = __builtin_nontemporal_load(&xt[2 * t + 1]);
        float ya[4], yb[4];
        {
            float h[4];
            #pragma unroll
            for (int j = 0; j < 4; j++)
                h[j] = xv0.x * tW[0*4+j] + xv0.y * tW[1*4+j] + xv0.z * tW[2*4+j] + xv0.w * tW[3*4+j] + tb[j];
            float mu = 0.25f * (h[0] + h[1] + h[2] + h[3]);
            float var = 0.f;
            #pragma unroll
            for (int j = 0; j < 4; j++) { float d = h[j] - mu; var += d * d; }
            float rr = rsqrtf(var * 0.25f + EPS);
            #pragma unroll
            for (int j = 0; j < 4; j++) ya[j] = fmaxf((h[j] - mu) * rr * tg[j] + tbeta[j], 0.f);
        }
        {
            float h[4];
            #pragma unroll
            for (int j = 0; j < 4; j++)
                h[j] = xv1.x * tW[0*4+j] + xv1.y * tW[1*4+j] + xv1.z * tW[2*4+j] + xv1.w * tW[3*4+j] + tb[j];
            float mu = 0.25f * (h[0] + h[1] + h[2] + h[3]);
            float var = 0.f;
            #pragma unroll
            for (int j = 0; j < 4; j++) { float d = h[j] - mu; var += d * d; }
            float rr = rsqrtf(var * 0.25f + EPS);
            #pragma unroll
            for (int j = 0; j < 4; j++) yb[j] = fmaxf((h[j] - mu) * rr * tg[j] + tbeta[j], 0.f);
        }
        int2 ids = *(const int2*)&idt[2 * t];
        if (ids.x == ids.y) {
            yb[0] = fmaxf(yb[0], ya[0]); yb[1] = fmaxf(yb[1], ya[1]);
            yb[2] = fmaxf(yb[2], ya[2]); yb[3] = fmaxf(yb[3], ya[3]);
        } else {
            unsigned int* p = (unsigned int*)&pool_t[(size_t)ids.x * 4];
            atomicMax(p + 0, __float_as_uint(ya[0]));
            atomicMax(p + 1, __float_as_uint(ya[1]));
            atomicMax(p + 2, __float_as_uint(ya[2]));
            atomicMax(p + 3, __float_as_uint(ya[3]));
        }
        id = ids.y;
        y0 = yb[0]; y1 = yb[1]; y2 = yb[2]; y3 = yb[3];
    } else if (t < NP_T / 2 + NP_L / 2) {
        int u = t - NP_T / 2;
        nfloat2 xv0 = __builtin_nontemporal_load(&xl[2 * u]);
        nfloat2 xv1 = __builtin_nontemporal_load(&xl[2 * u + 1]);
        float ya[2], yb[2];
        {
            float h0 = xv0.x * lW[0] + xv0.y * lW[2] + lb[0];
            float h1 = xv0.x * lW[1] + xv0.y * lW[3] + lb[1];
            float mu = 0.5f * (h0 + h1);
            float var = 0.5f * ((h0 - mu) * (h0 - mu) + (h1 - mu) * (h1 - mu));
            float rr = rsqrtf(var + EPS);
            ya[0] = fmaxf((h0 - mu) * rr * lg[0] + lbeta[0], 0.f);
            ya[1] = fmaxf((h1 - mu) * rr * lg[1] + lbeta[1], 0.f);
        }
        {
            float h0 = xv1.x * lW[0] + xv1.y * lW[2] + lb[0];
            float h1 = xv1.x * lW[1] + xv1.y * lW[3] + lb[1];
            float mu = 0.5f * (h0 + h1);
            float var = 0.5f * ((h0 - mu) * (h0 - mu) + (h1 - mu) * (h1 - mu));
            float rr = rsqrtf(var + EPS);
            yb[0] = fmaxf((h0 - mu) * rr * lg[0] + lbeta[0], 0.f);
            yb[1] = fmaxf((h1 - mu) * rr * lg[1] + lbeta[1], 0.f);
        }
        int2 ids = *(const int2*)&idl[2 * u];
        if (ids.x == ids.y) {
            yb[0] = fmaxf(yb[0], ya[0]); yb[1] = fmaxf(yb[1], ya[1]);
        } else {
            unsigned int* p = (unsigned int*)&pool_l[(size_t)ids.x * 2];
            atomicMax(p + 0, __float_as_uint(ya[0]));
            atomicMax(p + 1, __float_as_uint(ya[1]));
        }
        id = N_TRACK + ids.y;
        y0 = yb[0]; y1 = yb[1];
    }

    // wave-level segmented max scan over each thread's LAST point
    #pragma unroll
    for (int d = 1; d < 64; d <<= 1) {
        int oid = __shfl_down(id, d, 64);
        float o0 = __shfl_down(y0, d, 64);
        float o1 = __shfl_down(y1, d, 64);
        float o2 = __shfl_down(y2, d, 64);
        float o3 = __shfl_down(y3, d, 64);
        if (oid == id) {
            y0 = fmaxf(y0, o0); y1 = fmaxf(y1, o1);
            y2 = fmaxf(y2, o2); y3 = fmaxf(y3, o3);
        }
    }
    int pid = __shfl_up(id, 1, 64);
    bool head = (lane == 0) || (pid != id);
    if (id >= 0 && head) {
        if (id < N_TRACK) {
            unsigned int* p = (unsigned int*)&pool_t[(size_t)id * 4];
            atomicMax(p + 0, __float_as_uint(y0));
            atomicMax(p + 1, __float_as_uint(y1));
            atomicMax(p + 2, __float_as_uint(y2));
            atomicMax(p + 3, __float_as_uint(y3));
        } else {
            unsigned int* p = (unsigned int*)&pool_l[(size_t)(id - N_TRACK) * 2];
            atomicMax(p + 0, __float_as_uint(y0));
            atomicMax(p + 1, __float_as_uint(y1));
        }
    }
}

// ---------------- Node stage v2: 8 threads per node, 4 head-dwords each ----------------
// Thread t: node i = t>>3, slot = t&7 -> columns [slot*8, slot*8+8) of h (4 heads).
// Consecutive lanes write consecutive 16-B chunks -> perfectly coalesced stores.
// slot 7 computes heads 28,29 and zero-pads dwords 30,31.
__global__ void node_kernel(const float* __restrict__ pool_t, const float* __restrict__ pool_l,
                            const float* __restrict__ tW, const float* __restrict__ tb,
                            const float* __restrict__ lW, const float* __restrict__ lb,
                            const float* __restrict__ fcW,
                            unsigned int* __restrict__ hpack) {
    int t = blockIdx.x * blockDim.x + threadIdx.x;   // grid = N_ATT*8 exactly
    int i = t >> 3;
    int slot = t & 7;
    if (i >= N_ATT) return;

    float f[10];
    if (i < N_TRACK) {
        const float4 p = *(const float4*)(pool_t + (size_t)i * 4);
        #pragma unroll
        for (int j = 0; j < 10; j++)
            f[j] = p.x * tW[0*10+j] + p.y * tW[1*10+j] + p.z * tW[2*10+j] + p.w * tW[3*10+j] + tb[j];
    } else {
        const float2 p = *(const float2*)(pool_l + (size_t)(i - N_TRACK) * 2);
        #pragma unroll
        for (int j = 0; j < 10; j++)
            f[j] = p.x * lW[0*10+j] + p.y * lW[1*10+j] + lb[j];
    }

    int c0 = slot * 8;
    unsigned int r[4];
    #pragma unroll
    for (int q = 0; q < 4; q++) {
        unsigned int dw = 0u;
        int ca = c0 + 2 * q;
        if (ca < 60) {                       // slot 7: q=2,3 -> pad zeros
            float a0 = 0.f, a1 = 0.f;
            #pragma unroll
            for (int k = 0; k < 10; k++) {
                const float2 w = *(const float2*)(fcW + k * 60 + ca);  // 8B-aligned
                a0 += f[k] * w.x;
                a1 += f[k] * w.y;
            }
            unsigned int b0 = (unsigned int)__hip_bfloat16_raw(__float2bfloat16(a0)).x;
            unsigned int b1 = (unsigned int)__hip_bfloat16_raw(__float2bfloat16(a1)).x;
            dw = b0 | (b1 << 16);
        }
        r[q] = dw;
    }
    *(uint4*)(hpack + (size_t)i * REC_DW + slot * 4) = make_uint4(r[0], r[1], r[2], r[3]);
}

// ---------------- Edge softmax + aggregate: 32-lane group per dst, lane = head ----------------
// Batch-16 gathers into registers; batch softmax: tree-max (no serial per-edge
// chain), ONE accumulator rescale per batch, exp(-inf)=0 makes padding free.
__global__ void edge_kernel(const int* __restrict__ src, const int* __restrict__ off,
                            const unsigned int* __restrict__ hpack,
                            const float* __restrict__ attn_l, const float* __restrict__ attn_r,
                            const float* __restrict__ bias, float* __restrict__ out) {
    int grp = blockIdx.x * 8 + (threadIdx.x >> 5);
    int hh = threadIdx.x & 31;
    if (grp >= N_TRACK || hh >= HEADS) return;

    float al0 = attn_l[2 * hh], al1 = attn_l[2 * hh + 1];
    float ar0 = attn_r[2 * hh], ar1 = attn_r[2 * hh + 1];

    unsigned int dd = hpack[(size_t)grp * REC_DW + hh];
    float er = __uint_as_float(dd << 16) * ar0 + __uint_as_float(dd & 0xffff0000u) * ar1;

    int s = off[grp], e = off[grp + 1];
    float m = -INFINITY;
    float den_a = 0.f, n0_a = 0.f, n1_a = 0.f;
    float den_b = 0.f, n0_b = 0.f, n1_b = 0.f;

    for (int kk = s; kk < e; kk += 16) {
        int sv[16];
        #pragma unroll
        for (int j = 0; j < 16; j++) sv[j] = src[kk + j < e ? kk + j : kk];
        unsigned int d[16];
        #pragma unroll
        for (int j = 0; j < 16; j++) d[j] = hpack[(size_t)sv[j] * REC_DW + hh];

        float h0[16], h1[16], ev[16];
        #pragma unroll
        for (int j = 0; j < 16; j++) {
            h0[j] = __uint_as_float(d[j] << 16);
            h1[j] = __uint_as_float(d[j] & 0xffff0000u);
            float x = h0[j] * al0 + h1[j] * al1 + er;
            x = (x > 0.f) ? x : NEG_SLOPE * x;
            ev[j] = (kk + j < e) ? x : -INFINITY;
        }
        float mx[8];
        #pragma unroll
        for (int j = 0; j < 8; j++) mx[j] = fmaxf(ev[j], ev[j + 8]);
        #pragma unroll
        for (int j = 0; j < 4; j++) mx[j] = fmaxf(mx[j], mx[j + 4]);
        float bm = fmaxf(fmaxf(mx[0], mx[1]), fmaxf(mx[2], mx[3]));

        float nm = fmaxf(m, bm);
        float sc = (m > -INFINITY) ? __expf(m - nm) : 0.f;
        den_a *= sc; n0_a *= sc; n1_a *= sc;
        den_b *= sc; n0_b *= sc; n1_b *= sc;
        m = nm;
        #pragma unroll
        for (int j = 0; j < 16; j += 2) {
            float wa = __expf(ev[j] - nm);
            float wb = __expf(ev[j + 1] - nm);
            den_a += wa;            den_b += wb;
            n0_a += wa * h0[j];     n0_b += wb * h0[j + 1];
            n1_a += wa * h1[j];     n1_b += wb * h1[j + 1];
        }
    }

    float den = den_a + den_b, n0 = n0_a + n0_b, n1 = n1_a + n1_b;
    float o0 = 0.f, o1 = 0.f;
    if (den > 0.f) {
        float inv = 1.f / den;
        o0 = n0 * inv; o1 = n1 * inv;
    }
    nfloat2 v = { o0 + bias[2 * hh], o1 + bias[2 * hh + 1] };
    __builtin_nontemporal_store(v, (nfloat2*)out + (size_t)grp * HEADS + hh);
}

extern "C" void kernel_launch(void* const* d_in, const int* in_sizes, int n_in,
                              void* d_out, int out_size, void* d_ws, size_t ws_size,
                              hipStream_t stream) {
    const nfloat4* track_pts = (const nfloat4*)d_in[0];
    const nfloat2* lane_pts  = (const nfloat2*)d_in[1];
    const int* pt_track_id  = (const int*)d_in[2];
    const int* pt_lane_id   = (const int*)d_in[3];
    const int* att_src      = (const int*)d_in[4];
    const int* att_dst      = (const int*)d_in[5];
    const float* track_mlp_W = (const float*)d_in[6];
    const float* track_mlp_b = (const float*)d_in[7];
    const float* track_ln_g  = (const float*)d_in[8];
    const float* track_ln_b  = (const float*)d_in[9];
    const float* track_out_W = (const float*)d_in[10];
    const float* track_out_b = (const float*)d_in[11];
    const float* lane_mlp_W  = (const float*)d_in[12];
    const float* lane_mlp_b  = (const float*)d_in[13];
    const float* lane_ln_g   = (const float*)d_in[14];
    const float* lane_ln_b   = (const float*)d_in[15];
    const float* lane_out_W  = (const float*)d_in[16];
    const float* lane_out_b  = (const float*)d_in[17];
    const float* gat_fc_W    = (const float*)d_in[18];
    const float* gat_attn_l  = (const float*)d_in[19];
    const float* gat_attn_r  = (const float*)d_in[20];
    const float* gat_bias    = (const float*)d_in[21];
    float* out = (float*)d_out;

    // workspace layout (hpack 128B-aligned: offsets are multiples of 128 B from d_ws)
    float* pool_t = (float*)d_ws;                        // 200000 floats
    float* pool_l = pool_t + 200000;                     // 100000 floats
    int*   off    = (int*)(pool_l + 100000);             // 50001 ints (pad to 50016)
    unsigned int* hpack = (unsigned int*)(off + 50016);  // 100000 * 32 dwords (12.8 MB)

    // zero the pools (ReLU outputs >= 0, empty segments -> 0)
    (void)hipMemsetAsync(d_ws, 0, 300000 * sizeof(float), stream);

    point_kernel<<<(PT_THREADS + 255) / 256, 256, 0, stream>>>(
        track_pts, lane_pts, pt_track_id, pt_lane_id,
        track_mlp_W, track_mlp_b, track_ln_g, track_ln_b,
        lane_mlp_W, lane_mlp_b, lane_ln_g, lane_ln_b,
        att_dst, pool_t, pool_l, off);
    node_kernel<<<(N_ATT * 8) / 256, 256, 0, stream>>>(
        pool_t, pool_l, track_out_W, track_out_b, lane_out_W, lane_out_b,
        gat_fc_W, hpack);
    edge_kernel<<<(N_TRACK + 7) / 8, 256, 0, stream>>>(
        att_src, off, hpack, gat_attn_l, gat_attn_r, gat_bias, out);
}